// Round 14
// baseline (159.220 us; speedup 1.0000x reference)
//
#include <hip/hip_runtime.h>

// Problem constants (match reference).
#define BB   64
#define NN   900
#define MM   300
#define NC1  92          // NUM_CLASSES + 1
#define MQ   75          // float4 groups per m-row (300/4)
#define KN   4           // n-rows per thread
#define NCH  (NN / KN)   // 225

typedef float f32x2 __attribute__((ext_vector_type(2)));
typedef float f32x4 __attribute__((ext_vector_type(4)));

static __device__ __forceinline__ f32x2 min2(f32x2 a, f32x2 b) {
    return f32x2{ fminf(a.x, b.x), fminf(a.y, b.y) };
}
static __device__ __forceinline__ f32x2 max2(f32x2 a, f32x2 b) {
    return f32x2{ fmaxf(a.x, b.x), fmaxf(a.y, b.y) };
}

// Force 8 waves/SIMD capacity (VGPR cap 64): max TLP for latency hiding.
__global__ __launch_bounds__(256, 8) void cost_kernel(
    const float4* __restrict__ bbox_pred,   // [B*N] (cx,cy,w,h)
    const float*  __restrict__ labels_pred, // [B*N*92]
    const float4* __restrict__ bbox_gt,     // [B*M]
    const int4*   __restrict__ labels_gt,   // [B*M/4]
    float4*       __restrict__ out)         // [B*N*MQ]
{
    const int total = BB * NCH * MQ;        // 1,080,000
    int idx = blockIdx.x * blockDim.x + threadIdx.x;
    if (idx >= total) return;

    int mq   = idx % MQ;
    int rest = idx / MQ;
    int b    = rest / NCH;
    int nb   = rest % NCH;
    int bn0  = b * NN + nb * KN;

    // ---------- Phase 1: issue all loads up front ----------
    int4 lg = labels_gt[b * MQ + mq];

    float4 g4[4];
#pragma unroll
    for (int j = 0; j < 4; ++j)
        g4[j] = bbox_gt[b * MM + mq * 4 + j];

    float4 p4[KN];
#pragma unroll
    for (int k = 0; k < KN; ++k)
        p4[k] = bbox_pred[bn0 + k];

    int lbl[4] = { lg.x, lg.y, lg.z, lg.w };
    float cls1[KN][4];                       // 1 - cls, folded here
#pragma unroll
    for (int k = 0; k < KN; ++k) {
        const float* lp = labels_pred + (size_t)(bn0 + k) * NC1;
#pragma unroll
        for (int j = 0; j < 4; ++j)
            cls1[k][j] = 1.0f - lp[lbl[j]];
    }

    // ---------- Phase 2: gt state (packed) ----------
    f32x2 gc[4], gs[4], gu[4], gd1[4], gs1[4];
    float ga[4];
#pragma unroll
    for (int j = 0; j < 4; ++j) {
        float4 g = g4[j];
        gc[j]  = f32x2{ g.x, g.y };
        gs[j]  = f32x2{ g.z, g.w };
        gu[j]  = gc[j] - 0.5f * gs[j];
        gs1[j] = gs[j] + 1.0f;
        gd1[j] = gu[j] + gs1[j];
        ga[j]  = gs1[j].x * gs1[j].y;
    }

    // ---------- Phase 3: compute + store ----------
#pragma unroll
    for (int k = 0; k < KN; ++k) {
        float4 p = p4[k];
        f32x2 pc  = f32x2{ p.x, p.y };
        f32x2 ps  = f32x2{ p.z, p.w };
        f32x2 pu  = pc - 0.5f * ps;
        f32x2 ps1 = ps + 1.0f;
        f32x2 pd1 = pu + ps1;
        float parea = ps1.x * ps1.y;

        float res[4];
#pragma unroll
        for (int j = 0; j < 4; ++j) {
            f32x2 iwr = min2(pd1, gd1[j]) - max2(pu, gu[j]);
            f32x2 iw  = max2(iwr, f32x2{ 0.0f, 0.0f });
            float inter = iw.x * iw.y;

            f32x2 bw = (ps1 + gs1[j]) - iwr;      // bound-from-sum identity
            float barea = bw.x * bw.y;

            float uni   = (parea + ga[j]) - inter;
            float denom = uni * barea;
            float num   = inter * barea + uni * uni;   // iou+bg with ONE rcp
            float frac  = num * __builtin_amdgcn_rcpf(denom);

            f32x2 d1 = pc - gc[j];
            f32x2 d2 = ps - gs[j];
            float bbox = (fabsf(d1.x) + fabsf(d1.y))
                       + (fabsf(d2.x) + fabsf(d2.y));

            res[j] = (bbox + cls1[k][j]) - frac;
        }

        out[(size_t)(bn0 + k) * MQ + mq] =
            make_float4(res[0], res[1], res[2], res[3]);
    }
}

extern "C" void kernel_launch(void* const* d_in, const int* in_sizes, int n_in,
                              void* d_out, int out_size, void* d_ws, size_t ws_size,
                              hipStream_t stream) {
    const float4* bbox_pred   = (const float4*)d_in[0];
    const float*  labels_pred = (const float*) d_in[1];
    const float4* bbox_gt     = (const float4*)d_in[2];
    const int4*   labels_gt   = (const int4*)  d_in[3];
    float4*       out         = (float4*)d_out;

    const int total = BB * NCH * MQ;
    const int block = 256;
    const int grid  = (total + block - 1) / block;   // 4219 blocks
    cost_kernel<<<grid, block, 0, stream>>>(bbox_pred, labels_pred, bbox_gt,
                                            labels_gt, out);
}

// Round 15
// 31.385 us; speedup vs baseline: 5.0731x; 5.0731x over previous
//
#include <hip/hip_runtime.h>

// Problem constants (match reference).
#define BB   64
#define NN   900
#define MM   300
#define NC1  92          // NUM_CLASSES + 1
#define MQ   75          // float4 groups per m-row (300/4)
#define KN   4           // n-rows per thread
#define NCH  (NN / KN)   // 225

typedef float f32x2 __attribute__((ext_vector_type(2)));

static __device__ __forceinline__ f32x2 min2(f32x2 a, f32x2 b) {
    return f32x2{ fminf(a.x, b.x), fminf(a.y, b.y) };
}
static __device__ __forceinline__ f32x2 max2(f32x2 a, f32x2 b) {
    return f32x2{ fmaxf(a.x, b.x), fmaxf(a.y, b.y) };
}

__global__ __launch_bounds__(256) void cost_kernel(
    const float4* __restrict__ bbox_pred,   // [B*N] (cx,cy,w,h)
    const float*  __restrict__ labels_pred, // [B*N*92]
    const float4* __restrict__ bbox_gt,     // [B*M]
    const int4*   __restrict__ labels_gt,   // [B*M/4]
    float4*       __restrict__ out)         // [B*N*MQ]
{
    const int total = BB * NCH * MQ;        // 1,080,000
    int idx = blockIdx.x * blockDim.x + threadIdx.x;
    if (idx >= total) return;

    int mq   = idx % MQ;
    int rest = idx / MQ;
    int b    = rest / NCH;
    int nb   = rest % NCH;
    int bn0  = b * NN + nb * KN;

    // ---------- Phase 1: issue all loads up front ----------
    int4 lg = labels_gt[b * MQ + mq];       // in flight...

    float4 g4[4];
#pragma unroll
    for (int j = 0; j < 4; ++j)
        g4[j] = bbox_gt[b * MM + mq * 4 + j];

    float4 p4[KN];
#pragma unroll
    for (int k = 0; k < KN; ++k)
        p4[k] = bbox_pred[bn0 + k];

    // Line-touch prefetch of the 4 labels_pred rows: addresses depend only on
    // bn0, NOT on lg -> issues concurrently with the lg load, warming every
    // 64B line the lbl-dependent gathers can hit (row = 368B = <=7 lines).
    // Same bn0 across ~75 consecutive lanes -> broadcast, ~8 lines/wave.
    float touch = 0.0f;
#pragma unroll
    for (int k = 0; k < KN; ++k) {
        const float* lp = labels_pred + (size_t)(bn0 + k) * NC1;
#pragma unroll
        for (int o = 0; o < 96; o += 16)    // floats 0,16,32,48,64,80
            touch += lp[o];
        touch += lp[NC1 - 1];               // straddle line (rows not 64B-aligned)
    }
    asm volatile("" :: "v"(touch));         // keep touches live (no DCE)

    int lbl[4] = { lg.x, lg.y, lg.z, lg.w };
    float cls1[KN][4];                       // 1 - cls, folded here
#pragma unroll
    for (int k = 0; k < KN; ++k) {
        const float* lp = labels_pred + (size_t)(bn0 + k) * NC1;
#pragma unroll
        for (int j = 0; j < 4; ++j)
            cls1[k][j] = 1.0f - lp[lbl[j]];
    }

    // ---------- Phase 2: gt state (packed) ----------
    f32x2 gc[4], gs[4], gu[4], gd1[4], gs1[4];
    float ga[4];
#pragma unroll
    for (int j = 0; j < 4; ++j) {
        float4 g = g4[j];
        gc[j]  = f32x2{ g.x, g.y };
        gs[j]  = f32x2{ g.z, g.w };
        gu[j]  = gc[j] - 0.5f * gs[j];
        gs1[j] = gs[j] + 1.0f;
        gd1[j] = gu[j] + gs1[j];
        ga[j]  = gs1[j].x * gs1[j].y;
    }

    // ---------- Phase 3: compute + store ----------
#pragma unroll
    for (int k = 0; k < KN; ++k) {
        float4 p = p4[k];
        f32x2 pc  = f32x2{ p.x, p.y };
        f32x2 ps  = f32x2{ p.z, p.w };
        f32x2 pu  = pc - 0.5f * ps;
        f32x2 ps1 = ps + 1.0f;
        f32x2 pd1 = pu + ps1;
        float parea = ps1.x * ps1.y;

        float res[4];
#pragma unroll
        for (int j = 0; j < 4; ++j) {
            f32x2 iwr = min2(pd1, gd1[j]) - max2(pu, gu[j]);
            f32x2 iw  = max2(iwr, f32x2{ 0.0f, 0.0f });
            float inter = iw.x * iw.y;

            f32x2 bw = (ps1 + gs1[j]) - iwr;      // bound-from-sum identity
            float barea = bw.x * bw.y;

            float uni   = (parea + ga[j]) - inter;
            float denom = uni * barea;
            float num   = inter * barea + uni * uni;   // iou+bg with ONE rcp
            float frac  = num * __builtin_amdgcn_rcpf(denom);

            f32x2 d1 = pc - gc[j];
            f32x2 d2 = ps - gs[j];
            float bbox = (fabsf(d1.x) + fabsf(d1.y))
                       + (fabsf(d2.x) + fabsf(d2.y));

            res[j] = (bbox + cls1[k][j]) - frac;
        }

        out[(size_t)(bn0 + k) * MQ + mq] =
            make_float4(res[0], res[1], res[2], res[3]);
    }
}

extern "C" void kernel_launch(void* const* d_in, const int* in_sizes, int n_in,
                              void* d_out, int out_size, void* d_ws, size_t ws_size,
                              hipStream_t stream) {
    const float4* bbox_pred   = (const float4*)d_in[0];
    const float*  labels_pred = (const float*) d_in[1];
    const float4* bbox_gt     = (const float4*)d_in[2];
    const int4*   labels_gt   = (const int4*)  d_in[3];
    float4*       out         = (float4*)d_out;

    const int total = BB * NCH * MQ;
    const int block = 256;
    const int grid  = (total + block - 1) / block;   // 4219 blocks
    cost_kernel<<<grid, block, 0, stream>>>(bbox_pred, labels_pred, bbox_gt,
                                            labels_gt, out);
}

// Round 16
// 27.159 us; speedup vs baseline: 5.8626x; 1.1556x over previous
//
#include <hip/hip_runtime.h>

// Problem constants (match reference).
#define BB   64
#define NN   900
#define MM   300
#define NC1  92          // NUM_CLASSES + 1
#define MQ   75          // float4 groups per m-row (300/4)
#define KN   4           // n-rows per thread
#define NCH  (NN / KN)   // 225

typedef float f32x2 __attribute__((ext_vector_type(2)));

static __device__ __forceinline__ f32x2 min2(f32x2 a, f32x2 b) {
    return f32x2{ fminf(a.x, b.x), fminf(a.y, b.y) };
}
static __device__ __forceinline__ f32x2 max2(f32x2 a, f32x2 b) {
    return f32x2{ fmaxf(a.x, b.x), fmaxf(a.y, b.y) };
}

__global__ __launch_bounds__(256) void cost_kernel(
    const float4* __restrict__ bbox_pred,   // [B*N] (cx,cy,w,h)
    const float*  __restrict__ labels_pred, // [B*N*92]
    const float4* __restrict__ bbox_gt,     // [B*M]
    const int4*   __restrict__ labels_gt,   // [B*M/4]
    float4*       __restrict__ out)         // [B*N*MQ]
{
    const int total = BB * NCH * MQ;        // 1,080,000
    int idx = blockIdx.x * blockDim.x + threadIdx.x;
    if (idx >= total) return;

    int mq   = idx % MQ;
    int rest = idx / MQ;
    int b    = rest / NCH;
    int nb   = rest % NCH;
    int bn0  = b * NN + nb * KN;

    // ---------- Phase 1: issue all loads up front ----------
    int4 lg = labels_gt[b * MQ + mq];

    float4 g4[4];
#pragma unroll
    for (int j = 0; j < 4; ++j)
        g4[j] = bbox_gt[b * MM + mq * 4 + j];

    float4 p4[KN];
#pragma unroll
    for (int k = 0; k < KN; ++k)
        p4[k] = bbox_pred[bn0 + k];

    int lbl[4] = { lg.x, lg.y, lg.z, lg.w };
    float cls1[KN][4];                       // 1 - cls, folded here
#pragma unroll
    for (int k = 0; k < KN; ++k) {
        const float* lp = labels_pred + (size_t)(bn0 + k) * NC1;
#pragma unroll
        for (int j = 0; j < 4; ++j)
            cls1[k][j] = 1.0f - lp[lbl[j]];
    }

    // ---------- Phase 2: gt state (packed) ----------
    f32x2 gc[4], gs[4], gu[4], gd1[4], gs1[4];
    float ga[4];
#pragma unroll
    for (int j = 0; j < 4; ++j) {
        float4 g = g4[j];
        gc[j]  = f32x2{ g.x, g.y };
        gs[j]  = f32x2{ g.z, g.w };
        gu[j]  = gc[j] - 0.5f * gs[j];
        gs1[j] = gs[j] + 1.0f;
        gd1[j] = gu[j] + gs1[j];
        ga[j]  = gs1[j].x * gs1[j].y;
    }

    // ---------- Phase 3: compute + store ----------
#pragma unroll
    for (int k = 0; k < KN; ++k) {
        float4 p = p4[k];
        f32x2 pc  = f32x2{ p.x, p.y };
        f32x2 ps  = f32x2{ p.z, p.w };
        f32x2 pu  = pc - 0.5f * ps;
        f32x2 ps1 = ps + 1.0f;
        f32x2 pd1 = pu + ps1;
        float parea = ps1.x * ps1.y;

        float res[4];
#pragma unroll
        for (int j = 0; j < 4; ++j) {
            f32x2 iwr = min2(pd1, gd1[j]) - max2(pu, gu[j]);
            f32x2 iw  = max2(iwr, f32x2{ 0.0f, 0.0f });
            float inter = iw.x * iw.y;

            f32x2 bw = (ps1 + gs1[j]) - iwr;      // bound-from-sum identity
            float barea = bw.x * bw.y;

            float uni   = (parea + ga[j]) - inter;
            float denom = uni * barea;
            float num   = inter * barea + uni * uni;   // iou+bg with ONE rcp
            float frac  = num * __builtin_amdgcn_rcpf(denom);

            f32x2 d1 = pc - gc[j];
            f32x2 d2 = ps - gs[j];
            float bbox = (fabsf(d1.x) + fabsf(d1.y))
                       + (fabsf(d2.x) + fabsf(d2.y));

            res[j] = (bbox + cls1[k][j]) - frac;
        }

        out[(size_t)(bn0 + k) * MQ + mq] =
            make_float4(res[0], res[1], res[2], res[3]);
    }
}

extern "C" void kernel_launch(void* const* d_in, const int* in_sizes, int n_in,
                              void* d_out, int out_size, void* d_ws, size_t ws_size,
                              hipStream_t stream) {
    const float4* bbox_pred   = (const float4*)d_in[0];
    const float*  labels_pred = (const float*) d_in[1];
    const float4* bbox_gt     = (const float4*)d_in[2];
    const int4*   labels_gt   = (const int4*)  d_in[3];
    float4*       out         = (float4*)d_out;

    const int total = BB * NCH * MQ;
    const int block = 256;
    const int grid  = (total + block - 1) / block;   // 4219 blocks
    cost_kernel<<<grid, block, 0, stream>>>(bbox_pred, labels_pred, bbox_gt,
                                            labels_gt, out);
}